// Round 1
// baseline (1440.083 us; speedup 1.0000x reference)
//
#include <hip/hip_runtime.h>
#include <stdint.h>

#define NN 10000
#define DIMV 256
#define HID 512
#define NEDGE 320000

typedef __attribute__((ext_vector_type(8))) short bf16x8;
typedef __attribute__((ext_vector_type(4))) float f32x4;
typedef __attribute__((ext_vector_type(4))) unsigned short u16x4;

__device__ __forceinline__ unsigned short f2bf(float f) {
  union { float f; unsigned int u; } c; c.f = f;
  return (unsigned short)((c.u + 0x7FFFu + ((c.u >> 16) & 1u)) >> 16);
}

__device__ __forceinline__ bf16x8 bzero8() {
  bf16x8 r;
#pragma unroll
  for (int i = 0; i < 8; ++i) r[i] = 0;
  return r;
}

__device__ __forceinline__ bf16x8 pack8(const float* x) {
  bf16x8 r;
#pragma unroll
  for (int i = 0; i < 8; ++i) r[i] = (short)f2bf(x[i]);
  return r;
}

// ---------------------------------------------------------------------------
// K0: convert weights fp32 -> bf16, transposed to [out][k] layout
// ---------------------------------------------------------------------------
__global__ void k_conv(const float* __restrict__ W1, const float* __restrict__ W2,
                       const float* __restrict__ Wl1, const float* __restrict__ Wl2,
                       unsigned short* __restrict__ W1T, unsigned short* __restrict__ W2T,
                       unsigned short* __restrict__ Wl1T, unsigned short* __restrict__ Wl2T) {
  int i = blockIdx.x * 256 + threadIdx.x;  // grid covers 131072
  if (i < 131072) {
    { int k = i >> 9, o = i & 511; W1T[o * 256 + k] = f2bf(W1[i]); }  // W1 [256][512]
    { int k = i >> 8, o = i & 255; W2T[o * 512 + k] = f2bf(W2[i]); }  // W2 [512][256]
    if (i < 65536) {
      int k = i >> 8, o = i & 255;
      Wl1T[o * 256 + k] = f2bf(Wl1[i]);
      Wl2T[o * 256 + k] = f2bf(Wl2[i]);
    }
  }
}

// ---------------------------------------------------------------------------
// K1: v = relu(vc + relu(vc@W1+b1)@W2 + b2), write v_rm [N][256] bf16 and
//     vT [256][N] bf16 (transposed, as B-operand of A@v)
// 313 blocks x 256 thr; BM=32 rows/block; 4 waves: wr=wid&1 (row-tile),
// wc=wid>>1 (col half)
// ---------------------------------------------------------------------------
__launch_bounds__(256, 2)
__global__ void k_mlp(const float* __restrict__ vc,
                      const unsigned short* __restrict__ W1T, const float* __restrict__ b1,
                      const unsigned short* __restrict__ W2T, const float* __restrict__ b2,
                      unsigned short* __restrict__ v_rm, unsigned short* __restrict__ vT) {
  __shared__ __align__(16) char sm[65536];
  // [0,16K):  vcb  [32][256] bf16, slot^=(row&7)      (phase 1 A-operand)
  // [16K,48K): phase1 Bbuf [512][32] slot^=((c>>1)&3); then h [32][512] slot^=(row&7)
  // [48K,64K): phase2 Bbuf [256][32]
  const int t = threadIdx.x;
  const int lane = t & 63, wid = t >> 6;
  const int wr = wid & 1, wc = wid >> 1;
  const int r0 = blockIdx.x * 32;

  {  // stage vc tile -> bf16
    const int row = t >> 3, grow = r0 + row;
#pragma unroll
    for (int q = 0; q < 4; ++q) {
      const int slot = (t & 7) * 4 + q;
      float buf[8] = {0.f, 0.f, 0.f, 0.f, 0.f, 0.f, 0.f, 0.f};
      if (grow < NN) {
        const float4 x0 = *(const float4*)(vc + (size_t)grow * DIMV + slot * 8);
        const float4 x1 = *(const float4*)(vc + (size_t)grow * DIMV + slot * 8 + 4);
        buf[0] = x0.x; buf[1] = x0.y; buf[2] = x0.z; buf[3] = x0.w;
        buf[4] = x1.x; buf[5] = x1.y; buf[6] = x1.z; buf[7] = x1.w;
      }
      *(bf16x8*)(sm + row * 512 + ((slot ^ (row & 7)) * 16)) = pack8(buf);
    }
  }

  f32x4 acc1[16];
#pragma unroll
  for (int i = 0; i < 16; ++i) acc1[i] = (f32x4){0.f, 0.f, 0.f, 0.f};

  // phase 1: [32][256] @ [256][512], 8 K-steps of 32
  for (int step = 0; step < 8; ++step) {
    __syncthreads();
#pragma unroll
    for (int rr = 0; rr < 2; ++rr) {
      const int c = t + rr * 256;
      const unsigned short* srcp = W1T + c * 256 + step * 32;
#pragma unroll
      for (int q = 0; q < 4; ++q) {
        bf16x8 w = *(const bf16x8*)(srcp + q * 8);
        *(bf16x8*)(sm + 16384 + c * 64 + ((q ^ ((c >> 1) & 3)) * 16)) = w;
      }
    }
    __syncthreads();
    const int arow = 16 * wr + (lane & 15);
    const int aslot = step * 4 + (lane >> 4);
    const bf16x8 af = *(const bf16x8*)(sm + arow * 512 + ((aslot ^ (arow & 7)) * 16));
#pragma unroll
    for (int ct = 0; ct < 16; ++ct) {
      const int c = 256 * wc + 16 * ct + (lane & 15);
      const bf16x8 bfr =
          *(const bf16x8*)(sm + 16384 + c * 64 + ((((lane >> 4)) ^ ((c >> 1) & 3)) * 16));
      acc1[ct] = __builtin_amdgcn_mfma_f32_16x16x32_bf16(af, bfr, acc1[ct], 0, 0, 0);
    }
  }
  __syncthreads();
  // h = relu(acc1 + b1) -> bf16 LDS [32][512] at 16384, slot = c>>3 (64 slots/row)
#pragma unroll
  for (int ct = 0; ct < 16; ++ct) {
    const int c = 256 * wc + 16 * ct + (lane & 15);
    const float bb = b1[c];
#pragma unroll
    for (int r = 0; r < 4; ++r) {
      const int row = 16 * wr + (lane >> 4) * 4 + r;
      float v = fmaxf(acc1[ct][r] + bb, 0.f);
      const int slot = c >> 3;
      *(unsigned short*)(sm + 16384 + row * 1024 + ((slot ^ (row & 7)) * 16) + (c & 7) * 2) =
          f2bf(v);
    }
  }

  f32x4 acc2[8];
#pragma unroll
  for (int i = 0; i < 8; ++i) acc2[i] = (f32x4){0.f, 0.f, 0.f, 0.f};

  // phase 2: [32][512] @ [512][256], 16 K-steps of 32
  for (int step = 0; step < 16; ++step) {
    __syncthreads();
    {
      const int c = t;
      const unsigned short* srcp = W2T + c * 512 + step * 32;
#pragma unroll
      for (int q = 0; q < 4; ++q) {
        bf16x8 w = *(const bf16x8*)(srcp + q * 8);
        *(bf16x8*)(sm + 49152 + c * 64 + ((q ^ ((c >> 1) & 3)) * 16)) = w;
      }
    }
    __syncthreads();
    const int arow = 16 * wr + (lane & 15);
    const int aslot = step * 4 + (lane >> 4);  // 0..63
    const bf16x8 af = *(const bf16x8*)(sm + 16384 + arow * 1024 + ((aslot ^ (arow & 7)) * 16));
#pragma unroll
    for (int ct = 0; ct < 8; ++ct) {
      const int c = 128 * wc + 16 * ct + (lane & 15);
      const bf16x8 bfr =
          *(const bf16x8*)(sm + 49152 + c * 64 + ((((lane >> 4)) ^ ((c >> 1) & 3)) * 16));
      acc2[ct] = __builtin_amdgcn_mfma_f32_16x16x32_bf16(af, bfr, acc2[ct], 0, 0, 0);
    }
  }

  // epilogue: v = relu(vc + acc2 + b2)
  const int growbase = r0 + 16 * wr + (lane >> 4) * 4;
  if (growbase < NN) {
#pragma unroll
    for (int ct = 0; ct < 8; ++ct) {
      const int c = 128 * wc + 16 * ct + (lane & 15);
      const float bb = b2[c];
      u16x4 pk;
#pragma unroll
      for (int r = 0; r < 4; ++r) {
        const int grow = growbase + r;
        float v = acc2[ct][r] + bb + vc[(size_t)grow * DIMV + c];
        v = fmaxf(v, 0.f);
        const unsigned short hv = f2bf(v);
        v_rm[(size_t)grow * DIMV + c] = hv;
        pk[r] = hv;
      }
      *(u16x4*)(vT + (size_t)c * NN + growbase) = pk;  // 4 consecutive nodes, 8B store
    }
  }
}

// ---------------------------------------------------------------------------
// K2: Av = A @ v.  BM=64, BN=256, split-K=2 -> grid (157,2) = 314 blocks.
// A fp32 converted to bf16 in staging. Partial sums to avp[s].
// ---------------------------------------------------------------------------
__launch_bounds__(256, 2)
__global__ void k_av(const float* __restrict__ A, const unsigned short* __restrict__ vT,
                     float* __restrict__ avp) {
  __shared__ __align__(16) char sm[20480];  // Abuf [64][32] @0 (4KB), Vbuf [256][32] @4096 (16KB)
  const int t = threadIdx.x, lane = t & 63, wid = t >> 6;
  const int wr = wid & 1, wc = wid >> 1;
  const int r0 = blockIdx.x * 64;
  const int s = blockIdx.y;
  const int kbase = s * 5000;
  float* outp = avp + (size_t)s * NN * DIMV;

  f32x4 acc[2][8];
#pragma unroll
  for (int a = 0; a < 2; ++a)
#pragma unroll
    for (int b = 0; b < 8; ++b) acc[a][b] = (f32x4){0.f, 0.f, 0.f, 0.f};

  for (int step = 0; step < 157; ++step) {  // ceil(5000/32)
    const int k0 = step * 32;
    __syncthreads();
    {  // stage A tile (fp32 -> bf16)
      const int i = t >> 2, qh = t & 3;
      const int grow = r0 + i;
      const int kk = k0 + qh * 8;
      float buf[8] = {0.f, 0.f, 0.f, 0.f, 0.f, 0.f, 0.f, 0.f};
      if (grow < NN && kk < 5000) {
        const float* p = A + (size_t)grow * NN + kbase + kk;
        const float4 x0 = *(const float4*)p;
        const float4 x1 = *(const float4*)(p + 4);
        buf[0] = x0.x; buf[1] = x0.y; buf[2] = x0.z; buf[3] = x0.w;
        buf[4] = x1.x; buf[5] = x1.y; buf[6] = x1.z; buf[7] = x1.w;
      }
      *(bf16x8*)(sm + i * 64 + ((qh ^ ((i >> 1) & 3)) * 16)) = pack8(buf);
    }
    {  // stage V tile (already bf16; vT row stride = NN elements)
      const int c = t;
      const unsigned short* srcp = vT + (size_t)c * NN + kbase + k0;
#pragma unroll
      for (int q = 0; q < 4; ++q) {
        bf16x8 w = (k0 + q * 8 < 5000) ? *(const bf16x8*)(srcp + q * 8) : bzero8();
        *(bf16x8*)(sm + 4096 + c * 64 + ((q ^ ((c >> 1) & 3)) * 16)) = w;
      }
    }
    __syncthreads();
    bf16x8 af[2];
#pragma unroll
    for (int rt = 0; rt < 2; ++rt) {
      const int ar = 32 * wr + 16 * rt + (lane & 15);
      af[rt] = *(const bf16x8*)(sm + ar * 64 + ((((lane >> 4)) ^ ((ar >> 1) & 3)) * 16));
    }
#pragma unroll
    for (int ct = 0; ct < 8; ++ct) {
      const int c = 128 * wc + 16 * ct + (lane & 15);
      const bf16x8 bfr =
          *(const bf16x8*)(sm + 4096 + c * 64 + ((((lane >> 4)) ^ ((c >> 1) & 3)) * 16));
      acc[0][ct] = __builtin_amdgcn_mfma_f32_16x16x32_bf16(af[0], bfr, acc[0][ct], 0, 0, 0);
      acc[1][ct] = __builtin_amdgcn_mfma_f32_16x16x32_bf16(af[1], bfr, acc[1][ct], 0, 0, 0);
    }
  }

#pragma unroll
  for (int rt = 0; rt < 2; ++rt) {
    const int growbase = r0 + 32 * wr + 16 * rt + (lane >> 4) * 4;
    if (growbase < NN) {
#pragma unroll
      for (int ct = 0; ct < 8; ++ct) {
        const int c = 128 * wc + 16 * ct + (lane & 15);
#pragma unroll
        for (int r = 0; r < 4; ++r)
          outp[(size_t)(growbase + r) * DIMV + c] = acc[rt][ct][r];
      }
    }
  }
}

// ---------------------------------------------------------------------------
// K3: v2 = relu(v@Wl1+bl1) + relu((Av0+Av1)@Wl2+bl2); writes v2 (ws) and d_out
// ---------------------------------------------------------------------------
__launch_bounds__(256, 2)
__global__ void k_out(const unsigned short* __restrict__ v_rm, const float* __restrict__ avp,
                      const unsigned short* __restrict__ Wl1T, const float* __restrict__ bl1,
                      const unsigned short* __restrict__ Wl2T, const float* __restrict__ bl2,
                      float* __restrict__ v2, float* __restrict__ outb) {
  __shared__ __align__(16) char sm[65536];
  // [0,16K): vtile [32][256]; [16K,32K): avtile [32][256];
  // [32K,48K): Wl1 chunk [256][32]; [48K,64K): Wl2 chunk [256][32]
  const int t = threadIdx.x, lane = t & 63, wid = t >> 6;
  const int wr = wid & 1, wc = wid >> 1;
  const int r0 = blockIdx.x * 32;

  {
    const int row = t >> 3, grow = r0 + row;
#pragma unroll
    for (int q = 0; q < 4; ++q) {
      const int slot = (t & 7) * 4 + q;
      bf16x8 w = (grow < NN) ? *(const bf16x8*)(v_rm + (size_t)grow * DIMV + slot * 8) : bzero8();
      *(bf16x8*)(sm + row * 512 + ((slot ^ (row & 7)) * 16)) = w;
    }
#pragma unroll
    for (int q = 0; q < 4; ++q) {
      const int slot = (t & 7) * 4 + q;
      float buf[8] = {0.f, 0.f, 0.f, 0.f, 0.f, 0.f, 0.f, 0.f};
      if (grow < NN) {
        const float* p0 = avp + (size_t)grow * DIMV + slot * 8;
        const float* p1 = p0 + (size_t)NN * DIMV;
        const float4 a0 = *(const float4*)p0, a1 = *(const float4*)(p0 + 4);
        const float4 c0 = *(const float4*)p1, c1 = *(const float4*)(p1 + 4);
        buf[0] = a0.x + c0.x; buf[1] = a0.y + c0.y; buf[2] = a0.z + c0.z; buf[3] = a0.w + c0.w;
        buf[4] = a1.x + c1.x; buf[5] = a1.y + c1.y; buf[6] = a1.z + c1.z; buf[7] = a1.w + c1.w;
      }
      *(bf16x8*)(sm + 16384 + row * 512 + ((slot ^ (row & 7)) * 16)) = pack8(buf);
    }
  }

  f32x4 acc1[8], acc2[8];
#pragma unroll
  for (int i = 0; i < 8; ++i) {
    acc1[i] = (f32x4){0.f, 0.f, 0.f, 0.f};
    acc2[i] = (f32x4){0.f, 0.f, 0.f, 0.f};
  }

  for (int step = 0; step < 8; ++step) {
    __syncthreads();
    {
      const int c = t;
      const unsigned short* s1 = Wl1T + c * 256 + step * 32;
      const unsigned short* s2 = Wl2T + c * 256 + step * 32;
#pragma unroll
      for (int q = 0; q < 4; ++q) {
        const int ps = (q ^ ((c >> 1) & 3)) * 16;
        *(bf16x8*)(sm + 32768 + c * 64 + ps) = *(const bf16x8*)(s1 + q * 8);
        *(bf16x8*)(sm + 49152 + c * 64 + ps) = *(const bf16x8*)(s2 + q * 8);
      }
    }
    __syncthreads();
    const int arow = 16 * wr + (lane & 15);
    const int aslot = step * 4 + (lane >> 4);
    const bf16x8 a1 = *(const bf16x8*)(sm + arow * 512 + ((aslot ^ (arow & 7)) * 16));
    const bf16x8 a2 = *(const bf16x8*)(sm + 16384 + arow * 512 + ((aslot ^ (arow & 7)) * 16));
#pragma unroll
    for (int ct = 0; ct < 8; ++ct) {
      const int c = 128 * wc + 16 * ct + (lane & 15);
      const int bs = (((lane >> 4)) ^ ((c >> 1) & 3)) * 16;
      acc1[ct] = __builtin_amdgcn_mfma_f32_16x16x32_bf16(
          a1, *(const bf16x8*)(sm + 32768 + c * 64 + bs), acc1[ct], 0, 0, 0);
      acc2[ct] = __builtin_amdgcn_mfma_f32_16x16x32_bf16(
          a2, *(const bf16x8*)(sm + 49152 + c * 64 + bs), acc2[ct], 0, 0, 0);
    }
  }

  const int growbase = r0 + 16 * wr + (lane >> 4) * 4;
  if (growbase < NN) {
#pragma unroll
    for (int ct = 0; ct < 8; ++ct) {
      const int c = 128 * wc + 16 * ct + (lane & 15);
      const float u1 = bl1[c], u2 = bl2[c];
#pragma unroll
      for (int r = 0; r < 4; ++r) {
        const float x = fmaxf(acc1[ct][r] + u1, 0.f) + fmaxf(acc2[ct][r] + u2, 0.f);
        v2[(size_t)(growbase + r) * DIMV + c] = x;
        outb[(size_t)(growbase + r) * DIMV + c] = x;
      }
    }
  }
}

// ---------------------------------------------------------------------------
// K4: out[dst] += v2[src] per edge. 1 wave per edge, 4 floats per lane.
// ---------------------------------------------------------------------------
__global__ void k_scatter(const float* __restrict__ v2, const int* __restrict__ src,
                          const int* __restrict__ dst, float* __restrict__ outb) {
  const int tid = blockIdx.x * 256 + threadIdx.x;
  const int e = tid >> 6;
  if (e >= NEDGE) return;
  const int lane = tid & 63;
  const int sN = src[e], dN = dst[e];
  const float4 x = *(const float4*)(v2 + (size_t)sN * DIMV + lane * 4);
  float* o = outb + (size_t)dN * DIMV + lane * 4;
  atomicAdd(o + 0, x.x);
  atomicAdd(o + 1, x.y);
  atomicAdd(o + 2, x.z);
  atomicAdd(o + 3, x.w);
}

// ---------------------------------------------------------------------------
extern "C" void kernel_launch(void* const* d_in, const int* in_sizes, int n_in,
                              void* d_out, int out_size, void* d_ws, size_t ws_size,
                              hipStream_t stream) {
  const float* vc  = (const float*)d_in[0];
  const float* A   = (const float*)d_in[1];
  const int*   src = (const int*)d_in[2];
  const int*   dst = (const int*)d_in[3];
  const float* W1  = (const float*)d_in[4];
  const float* b1  = (const float*)d_in[5];
  const float* W2  = (const float*)d_in[6];
  const float* b2  = (const float*)d_in[7];
  const float* Wl1 = (const float*)d_in[8];
  const float* bl1 = (const float*)d_in[9];
  const float* Wl2 = (const float*)d_in[10];
  const float* bl2 = (const float*)d_in[11];
  float* outb = (float*)d_out;
  char* ws = (char*)d_ws;

  // ws carve (all 256B-aligned); total 41,746,432 bytes
  unsigned short* W1T  = (unsigned short*)(ws + 0);          // 512x256 bf16
  unsigned short* W2T  = (unsigned short*)(ws + 262144);     // 256x512
  unsigned short* Wl1T = (unsigned short*)(ws + 524288);     // 256x256
  unsigned short* Wl2T = (unsigned short*)(ws + 655360);     // 256x256
  unsigned short* vT   = (unsigned short*)(ws + 786432);     // [256][10000] bf16
  unsigned short* v_rm = (unsigned short*)(ws + 5906432);    // [10000][256] bf16
  float*          avp  = (float*)(ws + 11026432);            // 2 x [10000][256] f32
  float*          v2   = (float*)(ws + 31506432);            // [10000][256] f32

  hipLaunchKernelGGL(k_conv, dim3(512), dim3(256), 0, stream,
                     W1, W2, Wl1, Wl2, W1T, W2T, Wl1T, Wl2T);
  hipLaunchKernelGGL(k_mlp, dim3(313), dim3(256), 0, stream,
                     vc, W1T, b1, W2T, b2, v_rm, vT);
  hipLaunchKernelGGL(k_av, dim3(157, 2), dim3(256), 0, stream, A, vT, avp);
  hipLaunchKernelGGL(k_out, dim3(313), dim3(256), 0, stream,
                     v_rm, avp, Wl1T, bl1, Wl2T, bl2, v2, outb);
  hipLaunchKernelGGL(k_scatter, dim3(80000), dim3(256), 0, stream, v2, src, dst, outb);
}

// Round 2
// 478.672 us; speedup vs baseline: 3.0085x; 3.0085x over previous
//
#include <hip/hip_runtime.h>
#include <stdint.h>

#define NN 10000
#define DIMV 256
#define HID 512
#define NEDGE 320000

typedef __attribute__((ext_vector_type(8))) short bf16x8;
typedef __attribute__((ext_vector_type(4))) float f32x4;
typedef __attribute__((ext_vector_type(4))) unsigned short u16x4;

__device__ __forceinline__ unsigned short f2bf(float f) {
  union { float f; unsigned int u; } c; c.f = f;
  return (unsigned short)((c.u + 0x7FFFu + ((c.u >> 16) & 1u)) >> 16);
}

__device__ __forceinline__ bf16x8 bzero8() {
  bf16x8 r;
#pragma unroll
  for (int i = 0; i < 8; ++i) r[i] = 0;
  return r;
}

__device__ __forceinline__ bf16x8 pack8(const float* x) {
  bf16x8 r;
#pragma unroll
  for (int i = 0; i < 8; ++i) r[i] = (short)f2bf(x[i]);
  return r;
}

// ---------------------------------------------------------------------------
// K0: convert weights fp32 -> bf16, transposed to [out][k] layout
// ---------------------------------------------------------------------------
__global__ void k_conv(const float* __restrict__ W1, const float* __restrict__ W2,
                       const float* __restrict__ Wl1, const float* __restrict__ Wl2,
                       unsigned short* __restrict__ W1T, unsigned short* __restrict__ W2T,
                       unsigned short* __restrict__ Wl1T, unsigned short* __restrict__ Wl2T) {
  int i = blockIdx.x * 256 + threadIdx.x;  // grid covers 131072
  if (i < 131072) {
    { int k = i >> 9, o = i & 511; W1T[o * 256 + k] = f2bf(W1[i]); }  // W1 [256][512]
    { int k = i >> 8, o = i & 255; W2T[o * 512 + k] = f2bf(W2[i]); }  // W2 [512][256]
    if (i < 65536) {
      int k = i >> 8, o = i & 255;
      Wl1T[o * 256 + k] = f2bf(Wl1[i]);
      Wl2T[o * 256 + k] = f2bf(Wl2[i]);
    }
  }
}

// ---------------------------------------------------------------------------
// K1: v = relu(vc + relu(vc@W1+b1)@W2 + b2), write v_rm [N][256] bf16 and
//     vT [256][N] bf16 (transposed, as B-operand of A@v)
// ---------------------------------------------------------------------------
__launch_bounds__(256, 2)
__global__ void k_mlp(const float* __restrict__ vc,
                      const unsigned short* __restrict__ W1T, const float* __restrict__ b1,
                      const unsigned short* __restrict__ W2T, const float* __restrict__ b2,
                      unsigned short* __restrict__ v_rm, unsigned short* __restrict__ vT) {
  __shared__ __align__(16) char sm[65536];
  const int t = threadIdx.x;
  const int lane = t & 63, wid = t >> 6;
  const int wr = wid & 1, wc = wid >> 1;
  const int r0 = blockIdx.x * 32;

  {  // stage vc tile -> bf16
    const int row = t >> 3, grow = r0 + row;
#pragma unroll
    for (int q = 0; q < 4; ++q) {
      const int slot = (t & 7) * 4 + q;
      float buf[8] = {0.f, 0.f, 0.f, 0.f, 0.f, 0.f, 0.f, 0.f};
      if (grow < NN) {
        const float4 x0 = *(const float4*)(vc + (size_t)grow * DIMV + slot * 8);
        const float4 x1 = *(const float4*)(vc + (size_t)grow * DIMV + slot * 8 + 4);
        buf[0] = x0.x; buf[1] = x0.y; buf[2] = x0.z; buf[3] = x0.w;
        buf[4] = x1.x; buf[5] = x1.y; buf[6] = x1.z; buf[7] = x1.w;
      }
      *(bf16x8*)(sm + row * 512 + ((slot ^ (row & 7)) * 16)) = pack8(buf);
    }
  }

  f32x4 acc1[16];
#pragma unroll
  for (int i = 0; i < 16; ++i) acc1[i] = (f32x4){0.f, 0.f, 0.f, 0.f};

  // phase 1: [32][256] @ [256][512], 8 K-steps of 32
  for (int step = 0; step < 8; ++step) {
    __syncthreads();
#pragma unroll
    for (int rr = 0; rr < 2; ++rr) {
      const int c = t + rr * 256;
      const unsigned short* srcp = W1T + c * 256 + step * 32;
#pragma unroll
      for (int q = 0; q < 4; ++q) {
        bf16x8 w = *(const bf16x8*)(srcp + q * 8);
        *(bf16x8*)(sm + 16384 + c * 64 + ((q ^ ((c >> 1) & 3)) * 16)) = w;
      }
    }
    __syncthreads();
    const int arow = 16 * wr + (lane & 15);
    const int aslot = step * 4 + (lane >> 4);
    const bf16x8 af = *(const bf16x8*)(sm + arow * 512 + ((aslot ^ (arow & 7)) * 16));
#pragma unroll
    for (int ct = 0; ct < 16; ++ct) {
      const int c = 256 * wc + 16 * ct + (lane & 15);
      const bf16x8 bfr =
          *(const bf16x8*)(sm + 16384 + c * 64 + ((((lane >> 4)) ^ ((c >> 1) & 3)) * 16));
      acc1[ct] = __builtin_amdgcn_mfma_f32_16x16x32_bf16(af, bfr, acc1[ct], 0, 0, 0);
    }
  }
  __syncthreads();
  // h = relu(acc1 + b1) -> bf16 LDS [32][512] at 16384
#pragma unroll
  for (int ct = 0; ct < 16; ++ct) {
    const int c = 256 * wc + 16 * ct + (lane & 15);
    const float bb = b1[c];
#pragma unroll
    for (int r = 0; r < 4; ++r) {
      const int row = 16 * wr + (lane >> 4) * 4 + r;
      float v = fmaxf(acc1[ct][r] + bb, 0.f);
      const int slot = c >> 3;
      *(unsigned short*)(sm + 16384 + row * 1024 + ((slot ^ (row & 7)) * 16) + (c & 7) * 2) =
          f2bf(v);
    }
  }

  f32x4 acc2[8];
#pragma unroll
  for (int i = 0; i < 8; ++i) acc2[i] = (f32x4){0.f, 0.f, 0.f, 0.f};

  // phase 2: [32][512] @ [512][256], 16 K-steps of 32
  for (int step = 0; step < 16; ++step) {
    __syncthreads();
    {
      const int c = t;
      const unsigned short* srcp = W2T + c * 512 + step * 32;
#pragma unroll
      for (int q = 0; q < 4; ++q) {
        bf16x8 w = *(const bf16x8*)(srcp + q * 8);
        *(bf16x8*)(sm + 49152 + c * 64 + ((q ^ ((c >> 1) & 3)) * 16)) = w;
      }
    }
    __syncthreads();
    const int arow = 16 * wr + (lane & 15);
    const int aslot = step * 4 + (lane >> 4);
    const bf16x8 af = *(const bf16x8*)(sm + 16384 + arow * 1024 + ((aslot ^ (arow & 7)) * 16));
#pragma unroll
    for (int ct = 0; ct < 8; ++ct) {
      const int c = 128 * wc + 16 * ct + (lane & 15);
      const bf16x8 bfr =
          *(const bf16x8*)(sm + 49152 + c * 64 + ((((lane >> 4)) ^ ((c >> 1) & 3)) * 16));
      acc2[ct] = __builtin_amdgcn_mfma_f32_16x16x32_bf16(af, bfr, acc2[ct], 0, 0, 0);
    }
  }

  // epilogue: v = relu(vc + acc2 + b2)
  const int growbase = r0 + 16 * wr + (lane >> 4) * 4;
  if (growbase < NN) {
#pragma unroll
    for (int ct = 0; ct < 8; ++ct) {
      const int c = 128 * wc + 16 * ct + (lane & 15);
      const float bb = b2[c];
      u16x4 pk;
#pragma unroll
      for (int r = 0; r < 4; ++r) {
        const int grow = growbase + r;
        float v = acc2[ct][r] + bb + vc[(size_t)grow * DIMV + c];
        v = fmaxf(v, 0.f);
        const unsigned short hv = f2bf(v);
        v_rm[(size_t)grow * DIMV + c] = hv;
        pk[r] = hv;
      }
      *(u16x4*)(vT + (size_t)c * NN + growbase) = pk;
    }
  }
}

// ---------------------------------------------------------------------------
// K2: Av = A @ v.  BM=64, BN=256, split-K=2 -> grid (157,2).
// ---------------------------------------------------------------------------
__launch_bounds__(256, 2)
__global__ void k_av(const float* __restrict__ A, const unsigned short* __restrict__ vT,
                     float* __restrict__ avp) {
  __shared__ __align__(16) char sm[20480];  // Abuf [64][32] @0, Vbuf [256][32] @4096
  const int t = threadIdx.x, lane = t & 63, wid = t >> 6;
  const int wr = wid & 1, wc = wid >> 1;
  const int r0 = blockIdx.x * 64;
  const int s = blockIdx.y;
  const int kbase = s * 5000;
  float* outp = avp + (size_t)s * NN * DIMV;

  f32x4 acc[2][8];
#pragma unroll
  for (int a = 0; a < 2; ++a)
#pragma unroll
    for (int b = 0; b < 8; ++b) acc[a][b] = (f32x4){0.f, 0.f, 0.f, 0.f};

  for (int step = 0; step < 157; ++step) {  // ceil(5000/32)
    const int k0 = step * 32;
    __syncthreads();
    {  // stage A tile (fp32 -> bf16)
      const int i = t >> 2, qh = t & 3;
      const int grow = r0 + i;
      const int kk = k0 + qh * 8;
      float buf[8] = {0.f, 0.f, 0.f, 0.f, 0.f, 0.f, 0.f, 0.f};
      if (grow < NN && kk < 5000) {
        const float* p = A + (size_t)grow * NN + kbase + kk;
        const float4 x0 = *(const float4*)p;
        const float4 x1 = *(const float4*)(p + 4);
        buf[0] = x0.x; buf[1] = x0.y; buf[2] = x0.z; buf[3] = x0.w;
        buf[4] = x1.x; buf[5] = x1.y; buf[6] = x1.z; buf[7] = x1.w;
      }
      *(bf16x8*)(sm + i * 64 + ((qh ^ ((i >> 1) & 3)) * 16)) = pack8(buf);
    }
    {  // stage V tile
      const int c = t;
      const unsigned short* srcp = vT + (size_t)c * NN + kbase + k0;
#pragma unroll
      for (int q = 0; q < 4; ++q) {
        bf16x8 w = (k0 + q * 8 < 5000) ? *(const bf16x8*)(srcp + q * 8) : bzero8();
        *(bf16x8*)(sm + 4096 + c * 64 + ((q ^ ((c >> 1) & 3)) * 16)) = w;
      }
    }
    __syncthreads();
    bf16x8 af[2];
#pragma unroll
    for (int rt = 0; rt < 2; ++rt) {
      const int ar = 32 * wr + 16 * rt + (lane & 15);
      af[rt] = *(const bf16x8*)(sm + ar * 64 + ((((lane >> 4)) ^ ((ar >> 1) & 3)) * 16));
    }
#pragma unroll
    for (int ct = 0; ct < 8; ++ct) {
      const int c = 128 * wc + 16 * ct + (lane & 15);
      const bf16x8 bfr =
          *(const bf16x8*)(sm + 4096 + c * 64 + ((((lane >> 4)) ^ ((c >> 1) & 3)) * 16));
      acc[0][ct] = __builtin_amdgcn_mfma_f32_16x16x32_bf16(af[0], bfr, acc[0][ct], 0, 0, 0);
      acc[1][ct] = __builtin_amdgcn_mfma_f32_16x16x32_bf16(af[1], bfr, acc[1][ct], 0, 0, 0);
    }
  }

#pragma unroll
  for (int rt = 0; rt < 2; ++rt) {
    const int growbase = r0 + 32 * wr + 16 * rt + (lane >> 4) * 4;
    if (growbase < NN) {
#pragma unroll
      for (int ct = 0; ct < 8; ++ct) {
        const int c = 128 * wc + 16 * ct + (lane & 15);
#pragma unroll
        for (int r = 0; r < 4; ++r)
          outp[(size_t)(growbase + r) * DIMV + c] = acc[rt][ct][r];
      }
    }
  }
}

// ---------------------------------------------------------------------------
// K3: v2 = relu(v@Wl1+bl1) + relu((Av0+Av1)@Wl2+bl2); writes v2 (ws) and d_out
// ---------------------------------------------------------------------------
__launch_bounds__(256, 2)
__global__ void k_out(const unsigned short* __restrict__ v_rm, const float* __restrict__ avp,
                      const unsigned short* __restrict__ Wl1T, const float* __restrict__ bl1,
                      const unsigned short* __restrict__ Wl2T, const float* __restrict__ bl2,
                      float* __restrict__ v2, float* __restrict__ outb) {
  __shared__ __align__(16) char sm[65536];
  const int t = threadIdx.x, lane = t & 63, wid = t >> 6;
  const int wr = wid & 1, wc = wid >> 1;
  const int r0 = blockIdx.x * 32;

  {
    const int row = t >> 3, grow = r0 + row;
#pragma unroll
    for (int q = 0; q < 4; ++q) {
      const int slot = (t & 7) * 4 + q;
      bf16x8 w = (grow < NN) ? *(const bf16x8*)(v_rm + (size_t)grow * DIMV + slot * 8) : bzero8();
      *(bf16x8*)(sm + row * 512 + ((slot ^ (row & 7)) * 16)) = w;
    }
#pragma unroll
    for (int q = 0; q < 4; ++q) {
      const int slot = (t & 7) * 4 + q;
      float buf[8] = {0.f, 0.f, 0.f, 0.f, 0.f, 0.f, 0.f, 0.f};
      if (grow < NN) {
        const float* p0 = avp + (size_t)grow * DIMV + slot * 8;
        const float* p1 = p0 + (size_t)NN * DIMV;
        const float4 a0 = *(const float4*)p0, a1 = *(const float4*)(p0 + 4);
        const float4 c0 = *(const float4*)p1, c1 = *(const float4*)(p1 + 4);
        buf[0] = a0.x + c0.x; buf[1] = a0.y + c0.y; buf[2] = a0.z + c0.z; buf[3] = a0.w + c0.w;
        buf[4] = a1.x + c1.x; buf[5] = a1.y + c1.y; buf[6] = a1.z + c1.z; buf[7] = a1.w + c1.w;
      }
      *(bf16x8*)(sm + 16384 + row * 512 + ((slot ^ (row & 7)) * 16)) = pack8(buf);
    }
  }

  f32x4 acc1[8], acc2[8];
#pragma unroll
  for (int i = 0; i < 8; ++i) {
    acc1[i] = (f32x4){0.f, 0.f, 0.f, 0.f};
    acc2[i] = (f32x4){0.f, 0.f, 0.f, 0.f};
  }

  for (int step = 0; step < 8; ++step) {
    __syncthreads();
    {
      const int c = t;
      const unsigned short* s1 = Wl1T + c * 256 + step * 32;
      const unsigned short* s2 = Wl2T + c * 256 + step * 32;
#pragma unroll
      for (int q = 0; q < 4; ++q) {
        const int ps = (q ^ ((c >> 1) & 3)) * 16;
        *(bf16x8*)(sm + 32768 + c * 64 + ps) = *(const bf16x8*)(s1 + q * 8);
        *(bf16x8*)(sm + 49152 + c * 64 + ps) = *(const bf16x8*)(s2 + q * 8);
      }
    }
    __syncthreads();
    const int arow = 16 * wr + (lane & 15);
    const int aslot = step * 4 + (lane >> 4);
    const bf16x8 a1 = *(const bf16x8*)(sm + arow * 512 + ((aslot ^ (arow & 7)) * 16));
    const bf16x8 a2 = *(const bf16x8*)(sm + 16384 + arow * 512 + ((aslot ^ (arow & 7)) * 16));
#pragma unroll
    for (int ct = 0; ct < 8; ++ct) {
      const int c = 128 * wc + 16 * ct + (lane & 15);
      const int bs = (((lane >> 4)) ^ ((c >> 1) & 3)) * 16;
      acc1[ct] = __builtin_amdgcn_mfma_f32_16x16x32_bf16(
          a1, *(const bf16x8*)(sm + 32768 + c * 64 + bs), acc1[ct], 0, 0, 0);
      acc2[ct] = __builtin_amdgcn_mfma_f32_16x16x32_bf16(
          a2, *(const bf16x8*)(sm + 49152 + c * 64 + bs), acc2[ct], 0, 0, 0);
    }
  }

  const int growbase = r0 + 16 * wr + (lane >> 4) * 4;
  if (growbase < NN) {
#pragma unroll
    for (int ct = 0; ct < 8; ++ct) {
      const int c = 128 * wc + 16 * ct + (lane & 15);
      const float u1 = bl1[c], u2 = bl2[c];
#pragma unroll
      for (int r = 0; r < 4; ++r) {
        const float x = fmaxf(acc1[ct][r] + u1, 0.f) + fmaxf(acc2[ct][r] + u2, 0.f);
        v2[(size_t)(growbase + r) * DIMV + c] = x;
        outb[(size_t)(growbase + r) * DIMV + c] = x;
      }
    }
  }
}

// ---------------------------------------------------------------------------
// K4a: histogram of dst
// ---------------------------------------------------------------------------
__global__ void k_hist(const int* __restrict__ dst, int* __restrict__ counts) {
  const int e = blockIdx.x * 256 + threadIdx.x;
  if (e < NEDGE) atomicAdd(&counts[dst[e]], 1);
}

// ---------------------------------------------------------------------------
// K4b: exclusive scan of counts[10000] -> offsets[10001], cursor copy
// ---------------------------------------------------------------------------
__global__ void k_scan(const int* __restrict__ counts, int* __restrict__ offsets,
                       int* __restrict__ cursor) {
  __shared__ int sm[1024];
  __shared__ int carry;
  const int t = threadIdx.x;
  if (t == 0) carry = 0;
  __syncthreads();
  for (int base = 0; base < NN; base += 1024) {
    const int i = base + t;
    const int x = (i < NN) ? counts[i] : 0;
    sm[t] = x;
    __syncthreads();
    for (int off = 1; off < 1024; off <<= 1) {
      int y = (t >= off) ? sm[t - off] : 0;
      __syncthreads();
      sm[t] += y;
      __syncthreads();
    }
    const int excl = sm[t] - x + carry;
    if (i < NN) { offsets[i] = excl; cursor[i] = excl; }
    __syncthreads();
    if (t == 1023) carry += sm[1023];
    __syncthreads();
  }
  if (t == 0) offsets[NN] = carry;
}

// ---------------------------------------------------------------------------
// K4c: fill buckets with src ids
// ---------------------------------------------------------------------------
__global__ void k_fill(const int* __restrict__ src, const int* __restrict__ dst,
                       int* __restrict__ cursor, int* __restrict__ srcbuf) {
  const int e = blockIdx.x * 256 + threadIdx.x;
  if (e < NEDGE) {
    const int pos = atomicAdd(&cursor[dst[e]], 1);
    srcbuf[pos] = src[e];
  }
}

// ---------------------------------------------------------------------------
// K4d: gather-sum. One wave per dst node; lane owns 4 consecutive floats.
// out[n] += sum_{s in bucket(n)} v2[s]   (out already holds v2 from k_out)
// ---------------------------------------------------------------------------
__launch_bounds__(256)
__global__ void k_gather(const float* __restrict__ v2, const int* __restrict__ offsets,
                         const int* __restrict__ srcbuf, float* __restrict__ outb) {
  const int n = (blockIdx.x * 256 + threadIdx.x) >> 6;
  if (n >= NN) return;
  const int lane = threadIdx.x & 63;
  const int beg = offsets[n], end = offsets[n + 1];
  float4 acc = {0.f, 0.f, 0.f, 0.f};
  int j = beg;
  for (; j + 2 <= end; j += 2) {
    const int s0 = srcbuf[j], s1 = srcbuf[j + 1];
    const float4 x0 = *(const float4*)(v2 + (size_t)s0 * DIMV + lane * 4);
    const float4 x1 = *(const float4*)(v2 + (size_t)s1 * DIMV + lane * 4);
    acc.x += x0.x + x1.x; acc.y += x0.y + x1.y;
    acc.z += x0.z + x1.z; acc.w += x0.w + x1.w;
  }
  if (j < end) {
    const int s0 = srcbuf[j];
    const float4 x0 = *(const float4*)(v2 + (size_t)s0 * DIMV + lane * 4);
    acc.x += x0.x; acc.y += x0.y; acc.z += x0.z; acc.w += x0.w;
  }
  float* o = outb + (size_t)n * DIMV + lane * 4;
  float4 cur = *(const float4*)o;
  cur.x += acc.x; cur.y += acc.y; cur.z += acc.z; cur.w += acc.w;
  *(float4*)o = cur;
}

// ---------------------------------------------------------------------------
extern "C" void kernel_launch(void* const* d_in, const int* in_sizes, int n_in,
                              void* d_out, int out_size, void* d_ws, size_t ws_size,
                              hipStream_t stream) {
  const float* vc  = (const float*)d_in[0];
  const float* A   = (const float*)d_in[1];
  const int*   src = (const int*)d_in[2];
  const int*   dst = (const int*)d_in[3];
  const float* W1  = (const float*)d_in[4];
  const float* b1  = (const float*)d_in[5];
  const float* W2  = (const float*)d_in[6];
  const float* b2  = (const float*)d_in[7];
  const float* Wl1 = (const float*)d_in[8];
  const float* bl1 = (const float*)d_in[9];
  const float* Wl2 = (const float*)d_in[10];
  const float* bl2 = (const float*)d_in[11];
  float* outb = (float*)d_out;
  char* ws = (char*)d_ws;

  // ws carve; total ~41.75 MB
  unsigned short* W1T  = (unsigned short*)(ws + 0);          // 512x256 bf16
  unsigned short* W2T  = (unsigned short*)(ws + 262144);     // 256x512
  unsigned short* Wl1T = (unsigned short*)(ws + 524288);     // 256x256
  unsigned short* Wl2T = (unsigned short*)(ws + 655360);     // 256x256
  unsigned short* vT   = (unsigned short*)(ws + 786432);     // [256][10000] bf16 (dead after k_av)
  unsigned short* v_rm = (unsigned short*)(ws + 5906432);    // [10000][256] bf16
  float*          avp  = (float*)(ws + 11026432);            // 2 x [10000][256] f32
  float*          v2   = (float*)(ws + 31506432);            // [10000][256] f32

  // CSR arrays alias the vT region (only used after k_av has consumed vT)
  int* counts  = (int*)(ws + 786432);          // 10000 ints
  int* offsets = (int*)(ws + 829440);          // 10001 ints
  int* cursor  = (int*)(ws + 872448);          // 10000 ints
  int* srcbuf  = (int*)(ws + 915456);          // 320000 ints

  hipLaunchKernelGGL(k_conv, dim3(512), dim3(256), 0, stream,
                     W1, W2, Wl1, Wl2, W1T, W2T, Wl1T, Wl2T);
  hipLaunchKernelGGL(k_mlp, dim3(313), dim3(256), 0, stream,
                     vc, W1T, b1, W2T, b2, v_rm, vT);
  hipLaunchKernelGGL(k_av, dim3(157, 2), dim3(256), 0, stream, A, vT, avp);

  // CSR build (vT is dead from here on)
  hipMemsetAsync(counts, 0, NN * sizeof(int), stream);
  hipLaunchKernelGGL(k_hist, dim3((NEDGE + 255) / 256), dim3(256), 0, stream, dst, counts);
  hipLaunchKernelGGL(k_scan, dim3(1), dim3(1024), 0, stream, counts, offsets, cursor);
  hipLaunchKernelGGL(k_fill, dim3((NEDGE + 255) / 256), dim3(256), 0, stream,
                     src, dst, cursor, srcbuf);

  hipLaunchKernelGGL(k_out, dim3(313), dim3(256), 0, stream,
                     v_rm, avp, Wl1T, bl1, Wl2T, bl2, v2, outb);
  hipLaunchKernelGGL(k_gather, dim3((NN * 64 + 255) / 256), dim3(256), 0, stream,
                     v2, offsets, srcbuf, outb);
}